// Round 29
// baseline (80.477 us; speedup 1.0000x reference)
//
#include <hip/hip_runtime.h>
#include <math.h>

#define N_DIM 64
#define C_DIM 512
#define K_DIM 64
#define P_DIM 900
#define P_PAD 928          // 29 * 32 (agg K-steps of 32)
#define PTILES 15          // assign p-blocks of 64

typedef __attribute__((ext_vector_type(8))) short short8;   // 8 bf16 = 4 VGPR
typedef __attribute__((ext_vector_type(4))) float f32x4;    // MFMA C/D + x loads
typedef __attribute__((ext_vector_type(4))) uint  u32x4;

#define A2_ELEMS   ((size_t)N_DIM * K_DIM * P_PAD)

// fp32 -> bf16 bits, round-to-nearest-even (inputs finite)
__device__ inline ushort f2bf(float f) {
  uint u = __builtin_bit_cast(uint, f);
  u += 0x7FFFu + ((u >> 16) & 1u);
  return (ushort)(u >> 16);
}
__device__ inline uint pk2(float a, float b) {
  return (uint)f2bf(a) | ((uint)f2bf(b) << 16);
}

// ---------------------------------------------------------------------------
// Kernel A (v15 = r12 direct-load body + r28 XCD swizzle): logits GEMM via
// MFMA + fused L2-norm + softmax. NO x LDS, NO mid-loop barriers.
// r12 alone: 78us -- latency-bound (8 float4 in flight/wave vs ~900cyc cold
// DRAM). r28 swizzle proved sibling ptiles share rows via one XCD's L2
// (FETCH 85.7->59.3 MB). Combined: 14/15 of the strided loads become
// ~200cyc L2 hits -> ~3.5x effective-latency reduction where the LDS-staged
// structure (barrier-paced, 67us invariant) could not benefit.
// Pixel map p = p0 + 4*l15 + pt (float4 along p). ks loop fully unrolled
// (rule #20: runtime-indexed wfrag -> 64-VGPR scratch spill).
// ---------------------------------------------------------------------------
__global__ __launch_bounds__(256, 2) void netvlad_assign(
    const float* __restrict__ x, const float* __restrict__ w,
    ushort* __restrict__ a2, float* __restrict__ asum_part)
{
  const int bid  = blockIdx.x;
  const int xcd  = bid & 7;           // round-robin dispatch -> XCD id
  const int slot = bid >> 3;          // 0..119 within XCD
  const int n    = xcd + 8 * (slot / PTILES);
  const int bpt  = slot % PTILES;
  const int p0   = bpt * 64;
  const int tid = threadIdx.x, wave = tid >> 6, lane = tid & 63;
  const int l15 = lane & 15, lhi = lane >> 4;

  __shared__ float wredm[4][4][16];
  __shared__ float wreds[4][4][16];

  // ---- W fragment preload (fp32 -> bf16 regs), k-slot = ks*32 + lhi*8 + j
  short8 wfrag[16];
  const float* wrow = w + (size_t)(wave * 16 + l15) * C_DIM + lhi * 8;
#pragma unroll
  for (int ks = 0; ks < 16; ++ks) {
    f32x4 f0 = *(const f32x4*)(wrow + ks * 32);
    f32x4 f1 = *(const f32x4*)(wrow + ks * 32 + 4);
    u32x4 up;
    up[0] = pk2(f0[0], f0[1]); up[1] = pk2(f0[2], f0[3]);
    up[2] = pk2(f1[0], f1[1]); up[3] = pk2(f1[2], f1[3]);
    wfrag[ks] = __builtin_bit_cast(short8, up);
  }

  // ---- x load base: float4 along p at pb = p0 + 4*l15 (clamped, 16B-aligned)
  const float* xb = x + (size_t)n * C_DIM * P_DIM;
  int pb = p0 + 4 * l15;
  if (pb > P_DIM - 4) pb = P_DIM - 4;          // only last tile clamps
  const float* xbase = xb + pb + (size_t)(lhi * 8) * P_DIM;

  // ---- MFMA main loop: direct-global vector B-loads + fused ssq
  f32x4 acc[4];
#pragma unroll
  for (int pt = 0; pt < 4; ++pt) acc[pt] = (f32x4){0.f, 0.f, 0.f, 0.f};
  float ssqp[4] = {0.f, 0.f, 0.f, 0.f};

#pragma unroll
  for (int ks = 0; ks < 16; ++ks) {
    const float* src = xbase + (size_t)(ks * 32) * P_DIM;
    f32x4 xv0 = *(const f32x4*)(src + 0 * P_DIM);
    f32x4 xv1 = *(const f32x4*)(src + 1 * P_DIM);
    f32x4 xv2 = *(const f32x4*)(src + 2 * P_DIM);
    f32x4 xv3 = *(const f32x4*)(src + 3 * P_DIM);
    f32x4 xv4 = *(const f32x4*)(src + 4 * P_DIM);
    f32x4 xv5 = *(const f32x4*)(src + 5 * P_DIM);
    f32x4 xv6 = *(const f32x4*)(src + 6 * P_DIM);
    f32x4 xv7 = *(const f32x4*)(src + 7 * P_DIM);
#pragma unroll
    for (int pt = 0; pt < 4; ++pt) {
      ssqp[pt] += xv0[pt] * xv0[pt] + xv1[pt] * xv1[pt]
                + xv2[pt] * xv2[pt] + xv3[pt] * xv3[pt]
                + xv4[pt] * xv4[pt] + xv5[pt] * xv5[pt]
                + xv6[pt] * xv6[pt] + xv7[pt] * xv7[pt];
      u32x4 up;
      up[0] = pk2(xv0[pt], xv1[pt]); up[1] = pk2(xv2[pt], xv3[pt]);
      up[2] = pk2(xv4[pt], xv5[pt]); up[3] = pk2(xv6[pt], xv7[pt]);
      short8 xf = __builtin_bit_cast(short8, up);
      acc[pt] = __builtin_amdgcn_mfma_f32_16x16x32_bf16(wfrag[ks], xf, acc[pt], 0, 0, 0);
    }
  }

  // ---- invn per pixel: full ssq = sum over the 4 lhi octet-groups
  float linv[4];
#pragma unroll
  for (int pt = 0; pt < 4; ++pt) {
    float s = ssqp[pt];
    s += __shfl_xor(s, 16);
    s += __shfl_xor(s, 32);
    linv[pt] = 1.0f / fmaxf(sqrtf(s), 1e-12f);
  }

  // ---- softmax over k (64 values per pixel slot, cross-wave via LDS)
  float lg[4][4];
#pragma unroll
  for (int pt = 0; pt < 4; ++pt) {
    float m = -1e30f;
#pragma unroll
    for (int r = 0; r < 4; ++r) { lg[pt][r] = acc[pt][r] * linv[pt]; m = fmaxf(m, lg[pt][r]); }
    m = fmaxf(m, __shfl_xor(m, 16));
    m = fmaxf(m, __shfl_xor(m, 32));
    if (lhi == 0) wredm[wave][pt][l15] = m;
  }
  __syncthreads();
#pragma unroll
  for (int pt = 0; pt < 4; ++pt) {
    float m = fmaxf(fmaxf(wredm[0][pt][l15], wredm[1][pt][l15]),
                    fmaxf(wredm[2][pt][l15], wredm[3][pt][l15]));
    float s = 0.f;
#pragma unroll
    for (int r = 0; r < 4; ++r) { lg[pt][r] = __expf(lg[pt][r] - m); s += lg[pt][r]; }
    s += __shfl_xor(s, 16);
    s += __shfl_xor(s, 32);
    if (lhi == 0) wreds[wave][pt][l15] = s;
  }
  __syncthreads();

  ushort* a2b = a2 + (size_t)n * K_DIM * P_PAD;
  float asr[4] = {0.f, 0.f, 0.f, 0.f};
#pragma unroll
  for (int pt = 0; pt < 4; ++pt) {
    float stot = wreds[0][pt][l15] + wreds[1][pt][l15] +
                 wreds[2][pt][l15] + wreds[3][pt][l15];
    float rs = 1.0f / stot;
    int p = p0 + 4 * l15 + pt;          // vector-load pixel mapping
    bool vv = p < P_DIM;
#pragma unroll
    for (int r = 0; r < 4; ++r) {
      float a = lg[pt][r] * rs;
      if (vv) asr[r] += a;
      if (p < P_PAD) {
        int k = wave * 16 + lhi * 4 + r;
        a2b[(size_t)k * P_PAD + p] = vv ? f2bf(a * linv[pt]) : (ushort)0;
      }
    }
  }
#pragma unroll
  for (int r = 0; r < 4; ++r) {
    float v = asr[r];
    v += __shfl_xor(v, 1); v += __shfl_xor(v, 2);
    v += __shfl_xor(v, 4); v += __shfl_xor(v, 8);
    if (l15 == 0) {
      int k = wave * 16 + lhi * 4 + r;
      asum_part[((size_t)n * K_DIM + k) * PTILES + bpt] = v;
    }
  }
}

// ---------------------------------------------------------------------------
// Kernel B: agg[n,k,c] = sum_p a2[k,p]*x[c,p] via MFMA (x L3-hot after A).
// Fused epilogue: out = acc - asum*centroid.
// ---------------------------------------------------------------------------
__global__ __launch_bounds__(256, 4) void netvlad_agg(
    const float* __restrict__ x, const ushort* __restrict__ a2,
    const float* __restrict__ asum_part, const float* __restrict__ cent,
    float* __restrict__ out)
{
  const int n = blockIdx.y, ct = blockIdx.x, c0 = ct * 64;
  const int tid = threadIdx.x, wave = tid >> 6, lane = tid & 63;
  const int l15 = lane & 15, lhi = lane >> 4;

  __shared__ float asum_s[64];
  if (tid < 64) {
    const float* ap = asum_part + ((size_t)n * K_DIM + tid) * PTILES;
    float s = 0.f;
#pragma unroll
    for (int j = 0; j < PTILES; ++j) s += ap[j];
    asum_s[tid] = s;
  }
  __syncthreads();

  f32x4 acc[4];
#pragma unroll
  for (int mt = 0; mt < 4; ++mt) acc[mt] = (f32x4){0.f, 0.f, 0.f, 0.f};

  const float*  xrow = x + (size_t)n * C_DIM * P_DIM
                         + (size_t)(c0 + wave * 16 + l15) * P_DIM;
  const ushort* ab   = a2 + (size_t)n * K_DIM * P_PAD;

  for (int ks = 0; ks < 29; ++ks) {
    int pb = ks * 32 + lhi * 8;
    short8 bfrag;
    if (pb + 8 <= P_DIM) {
      f32x4 f0 = *(const f32x4*)(xrow + pb);
      f32x4 f1 = *(const f32x4*)(xrow + pb + 4);
      u32x4 up;
      up[0] = pk2(f0[0], f0[1]); up[1] = pk2(f0[2], f0[3]);
      up[2] = pk2(f1[0], f1[1]); up[3] = pk2(f1[2], f1[3]);
      bfrag = __builtin_bit_cast(short8, up);
    } else {
#pragma unroll
      for (int j = 0; j < 8; ++j)
        bfrag[j] = (pb + j < P_DIM) ? (short)f2bf(xrow[pb + j]) : (short)0;
    }
#pragma unroll
    for (int mt = 0; mt < 4; ++mt) {
      short8 afrag = *(const short8*)(ab + (size_t)(mt * 16 + l15) * P_PAD
                                         + ks * 32 + lhi * 8);
      acc[mt] = __builtin_amdgcn_mfma_f32_16x16x32_bf16(afrag, bfrag, acc[mt], 0, 0, 0);
    }
  }

  const int c = c0 + wave * 16 + l15;
#pragma unroll
  for (int mt = 0; mt < 4; ++mt) {
#pragma unroll
    for (int r = 0; r < 4; ++r) {
      int k = mt * 16 + lhi * 4 + r;
      out[((size_t)n * K_DIM + k) * C_DIM + c] =
          acc[mt][r] - asum_s[k] * cent[(size_t)k * C_DIM + c];
    }
  }
}

extern "C" void kernel_launch(void* const* d_in, const int* in_sizes, int n_in,
                              void* d_out, int out_size, void* d_ws, size_t ws_size,
                              hipStream_t stream) {
  const float* x    = (const float*)d_in[0];
  const float* w    = (const float*)d_in[1];
  const float* cent = (const float*)d_in[2];
  float* out = (float*)d_out;

  ushort* a2        = (ushort*)d_ws;
  float*  asum_part = (float*)((char*)d_ws + A2_ELEMS * sizeof(ushort));

  netvlad_assign<<<dim3(PTILES * N_DIM), 256, 0, stream>>>(x, w, a2, asum_part);
  netvlad_agg   <<<dim3(8, N_DIM),       256, 0, stream>>>(x, a2, asum_part, cent, out);
}

// Round 30
// 77.484 us; speedup vs baseline: 1.0386x; 1.0386x over previous
//
#include <hip/hip_runtime.h>
#include <math.h>

#define N_DIM 64
#define C_DIM 512
#define K_DIM 64
#define P_DIM 900
#define P_PAD 928          // 29 * 32 (agg K-steps of 32)
#define PTILES 15          // assign p-blocks of 64

typedef __attribute__((ext_vector_type(8))) short short8;   // 8 bf16 = 4 VGPR
typedef __attribute__((ext_vector_type(4))) float f32x4;    // MFMA C/D + x loads
typedef __attribute__((ext_vector_type(4))) uint  u32x4;

#define A2_ELEMS   ((size_t)N_DIM * K_DIM * P_PAD)

// fp32 -> bf16 bits, round-to-nearest-even (inputs finite)
__device__ inline ushort f2bf(float f) {
  uint u = __builtin_bit_cast(uint, f);
  u += 0x7FFFu + ((u >> 16) & 1u);
  return (ushort)(u >> 16);
}
__device__ inline uint pk2(float a, float b) {
  return (uint)f2bf(a) | ((uint)f2bf(b) << 16);
}

// async global->LDS DMA, 16B per lane; LDS dest = wave-uniform base + lane*16
__device__ __forceinline__ void gload16(const float* g, float* lds_base) {
  __builtin_amdgcn_global_load_lds(
      (const __attribute__((address_space(1))) void*)g,
      (__attribute__((address_space(3))) void*)lds_base, 16, 0, 0);
}

// ---------------------------------------------------------------------------
// Kernel A (r28 best config): counted-vmcnt LDS-staged MFMA GEMM + fused
// L2-norm + softmax, with bijective XCD-aware block swizzle (T1).
// All 15 ptiles of image n run on XCD n%8 in adjacent slots -> that XCD's
// L2 assembles each 3600B row once for 15 consumers (FETCH 85.7->59.3 MB).
// T4 pipeline: raw s_barrier + vmcnt(8) keeps the 8 prefetch loads/wave in
// flight across barrier+compute. Chunks 128c x 64p = 32 KB, double-buffered.
// ks loops fully unrolled (rule #20: runtime-indexed wfrag -> scratch).
// Measured: assign ~67us, total 77.7us -- best of 15 structural variants;
// the c-strided gather shape caps at ~1 TB/s on this chip regardless of
// structure/temperature (r12,r16,r18,r19,r26,r29), and the transpose route
// independently converges to the same ~78us total (r20-r27).
// ---------------------------------------------------------------------------
__global__ __launch_bounds__(256, 2) void netvlad_assign(
    const float* __restrict__ x, const float* __restrict__ w,
    ushort* __restrict__ a2, float* __restrict__ asum_part)
{
  const int bid  = blockIdx.x;
  const int xcd  = bid & 7;           // dispatch round-robin -> XCD id
  const int slot = bid >> 3;          // 0..119 within XCD
  const int n    = xcd + 8 * (slot / PTILES);
  const int bpt  = slot % PTILES;
  const int p0   = bpt * 64;
  const int tid = threadIdx.x, wv = tid >> 6, lane = tid & 63;
  const int l15 = lane & 15, lhi = lane >> 4;

  __shared__ float xs[2][8192];       // 2 x 32 KB chunk buffers [128 c][64 p]
  __shared__ float wredm[4][4][16];
  __shared__ float wreds[4][4][16];

  // ---- W fragment preload (fp32 -> bf16 regs), k-slot = ks*32 + lhi*8 + j
  short8 wfrag[16];
  const float* wrow = w + (size_t)(wv * 16 + l15) * C_DIM + lhi * 8;
#pragma unroll
  for (int ks = 0; ks < 16; ++ks) {
    f32x4 f0 = *(const f32x4*)(wrow + ks * 32);
    f32x4 f1 = *(const f32x4*)(wrow + ks * 32 + 4);
    u32x4 up;
    up[0] = pk2(f0[0], f0[1]); up[1] = pk2(f0[2], f0[3]);
    up[2] = pk2(f1[0], f1[1]); up[3] = pk2(f1[2], f1[3]);
    wfrag[ks] = __builtin_bit_cast(short8, up);
  }

  // ---- staging geometry: seg = 4 c-rows x 64 p = 1 KB per gload16
  const float* xb = x + (size_t)n * C_DIM * P_DIM;
  int pld = p0 + (lane & 15) * 4;
  if (pld > P_DIM - 4) pld = P_DIM - 4;   // clamp (dup pixels, gated later)
  const int rquad = lane >> 4;            // row-within-segment (0..3)

  // stage chunk ch (128 c-rows) into buffer b: 32 segments, wave wv does 8
#define STAGE(b, ch)                                                           \
  {                                                                            \
    _Pragma("unroll")                                                          \
    for (int i = 0; i < 8; ++i) {                                              \
      int seg = wv + 4 * i;                                                    \
      int rr  = (ch) * 128 + seg * 4 + rquad;                                  \
      gload16(xb + (size_t)rr * P_DIM + pld, &xs[b][seg * 256]);               \
    }                                                                          \
  }

  f32x4 acc[4];
#pragma unroll
  for (int pt = 0; pt < 4; ++pt) acc[pt] = (f32x4){0.f, 0.f, 0.f, 0.f};
  float ssqp[4] = {0.f, 0.f, 0.f, 0.f};

  STAGE(0, 0);
#pragma unroll
  for (int ch = 0; ch < 4; ++ch) {
    if (ch + 1 < 4) STAGE((ch + 1) & 1, ch + 1);
    // counted wait: only the current chunk's 8 loads/wave must land;
    // the 8 prefetch loads stay in flight across barrier + compute (T4).
    if (ch < 3) asm volatile("s_waitcnt vmcnt(8)" ::: "memory");
    else        asm volatile("s_waitcnt vmcnt(0)" ::: "memory");
    __builtin_amdgcn_sched_barrier(0);
    __builtin_amdgcn_s_barrier();       // raw barrier: no vmcnt(0) drain
    const float* buf = xs[ch & 1];
#pragma unroll
    for (int ks = 0; ks < 4; ++ks) {
      f32x4 rd[8];
#pragma unroll
      for (int j = 0; j < 8; ++j)
        rd[j] = *(const f32x4*)&buf[(ks * 32 + 8 * lhi + j) * 64 + l15 * 4];
#pragma unroll
      for (int pt = 0; pt < 4; ++pt) {
        ssqp[pt] += rd[0][pt] * rd[0][pt] + rd[1][pt] * rd[1][pt]
                  + rd[2][pt] * rd[2][pt] + rd[3][pt] * rd[3][pt]
                  + rd[4][pt] * rd[4][pt] + rd[5][pt] * rd[5][pt]
                  + rd[6][pt] * rd[6][pt] + rd[7][pt] * rd[7][pt];
        u32x4 up;
        up[0] = pk2(rd[0][pt], rd[1][pt]); up[1] = pk2(rd[2][pt], rd[3][pt]);
        up[2] = pk2(rd[4][pt], rd[5][pt]); up[3] = pk2(rd[6][pt], rd[7][pt]);
        short8 xf = __builtin_bit_cast(short8, up);
        acc[pt] = __builtin_amdgcn_mfma_f32_16x16x32_bf16(
                      wfrag[ch * 4 + ks], xf, acc[pt], 0, 0, 0);
      }
    }
    __builtin_amdgcn_s_barrier();       // all reads done before buf reuse
  }
#undef STAGE

  // ---- invn per pixel: full ssq = sum over the 4 lhi octet-groups
  float linv[4];
#pragma unroll
  for (int pt = 0; pt < 4; ++pt) {
    float s = ssqp[pt];
    s += __shfl_xor(s, 16);
    s += __shfl_xor(s, 32);
    linv[pt] = 1.0f / fmaxf(sqrtf(s), 1e-12f);
  }

  // ---- softmax over k (64 values per pixel slot, cross-wave via LDS)
  float lg[4][4];
#pragma unroll
  for (int pt = 0; pt < 4; ++pt) {
    float m = -1e30f;
#pragma unroll
    for (int r = 0; r < 4; ++r) { lg[pt][r] = acc[pt][r] * linv[pt]; m = fmaxf(m, lg[pt][r]); }
    m = fmaxf(m, __shfl_xor(m, 16));
    m = fmaxf(m, __shfl_xor(m, 32));
    if (lhi == 0) wredm[wv][pt][l15] = m;
  }
  __syncthreads();
#pragma unroll
  for (int pt = 0; pt < 4; ++pt) {
    float m = fmaxf(fmaxf(wredm[0][pt][l15], wredm[1][pt][l15]),
                    fmaxf(wredm[2][pt][l15], wredm[3][pt][l15]));
    float s = 0.f;
#pragma unroll
    for (int r = 0; r < 4; ++r) { lg[pt][r] = __expf(lg[pt][r] - m); s += lg[pt][r]; }
    s += __shfl_xor(s, 16);
    s += __shfl_xor(s, 32);
    if (lhi == 0) wreds[wv][pt][l15] = s;
  }
  __syncthreads();

  ushort* a2b = a2 + (size_t)n * K_DIM * P_PAD;
  float asr[4] = {0.f, 0.f, 0.f, 0.f};
#pragma unroll
  for (int pt = 0; pt < 4; ++pt) {
    float stot = wreds[0][pt][l15] + wreds[1][pt][l15] +
                 wreds[2][pt][l15] + wreds[3][pt][l15];
    float rs = 1.0f / stot;
    int p = p0 + 4 * l15 + pt;          // vector-load pixel mapping
    bool vv = p < P_DIM;
#pragma unroll
    for (int r = 0; r < 4; ++r) {
      float a = lg[pt][r] * rs;
      if (vv) asr[r] += a;
      if (p < P_PAD) {
        int k = wv * 16 + lhi * 4 + r;
        a2b[(size_t)k * P_PAD + p] = vv ? f2bf(a * linv[pt]) : (ushort)0;
      }
    }
  }
#pragma unroll
  for (int r = 0; r < 4; ++r) {
    float v = asr[r];
    v += __shfl_xor(v, 1); v += __shfl_xor(v, 2);
    v += __shfl_xor(v, 4); v += __shfl_xor(v, 8);
    if (l15 == 0) {
      int k = wv * 16 + lhi * 4 + r;
      asum_part[((size_t)n * K_DIM + k) * PTILES + bpt] = v;
    }
  }
}

// ---------------------------------------------------------------------------
// Kernel B: agg[n,k,c] = sum_p a2[k,p]*x[c,p] via MFMA (x L3-hot after A).
// Fused epilogue: out = acc - asum*centroid.
// ---------------------------------------------------------------------------
__global__ __launch_bounds__(256, 4) void netvlad_agg(
    const float* __restrict__ x, const ushort* __restrict__ a2,
    const float* __restrict__ asum_part, const float* __restrict__ cent,
    float* __restrict__ out)
{
  const int n = blockIdx.y, ct = blockIdx.x, c0 = ct * 64;
  const int tid = threadIdx.x, wave = tid >> 6, lane = tid & 63;
  const int l15 = lane & 15, lhi = lane >> 4;

  __shared__ float asum_s[64];
  if (tid < 64) {
    const float* ap = asum_part + ((size_t)n * K_DIM + tid) * PTILES;
    float s = 0.f;
#pragma unroll
    for (int j = 0; j < PTILES; ++j) s += ap[j];
    asum_s[tid] = s;
  }
  __syncthreads();

  f32x4 acc[4];
#pragma unroll
  for (int mt = 0; mt < 4; ++mt) acc[mt] = (f32x4){0.f, 0.f, 0.f, 0.f};

  const float*  xrow = x + (size_t)n * C_DIM * P_DIM
                         + (size_t)(c0 + wave * 16 + l15) * P_DIM;
  const ushort* ab   = a2 + (size_t)n * K_DIM * P_PAD;

  for (int ks = 0; ks < 29; ++ks) {
    int pb = ks * 32 + lhi * 8;
    short8 bfrag;
    if (pb + 8 <= P_DIM) {
      f32x4 f0 = *(const f32x4*)(xrow + pb);
      f32x4 f1 = *(const f32x4*)(xrow + pb + 4);
      u32x4 up;
      up[0] = pk2(f0[0], f0[1]); up[1] = pk2(f0[2], f0[3]);
      up[2] = pk2(f1[0], f1[1]); up[3] = pk2(f1[2], f1[3]);
      bfrag = __builtin_bit_cast(short8, up);
    } else {
#pragma unroll
      for (int j = 0; j < 8; ++j)
        bfrag[j] = (pb + j < P_DIM) ? (short)f2bf(xrow[pb + j]) : (short)0;
    }
#pragma unroll
    for (int mt = 0; mt < 4; ++mt) {
      short8 afrag = *(const short8*)(ab + (size_t)(mt * 16 + l15) * P_PAD
                                         + ks * 32 + lhi * 8);
      acc[mt] = __builtin_amdgcn_mfma_f32_16x16x32_bf16(afrag, bfrag, acc[mt], 0, 0, 0);
    }
  }

  const int c = c0 + wave * 16 + l15;
#pragma unroll
  for (int mt = 0; mt < 4; ++mt) {
#pragma unroll
    for (int r = 0; r < 4; ++r) {
      int k = mt * 16 + lhi * 4 + r;
      out[((size_t)n * K_DIM + k) * C_DIM + c] =
          acc[mt][r] - asum_s[k] * cent[(size_t)k * C_DIM + c];
    }
  }
}

extern "C" void kernel_launch(void* const* d_in, const int* in_sizes, int n_in,
                              void* d_out, int out_size, void* d_ws, size_t ws_size,
                              hipStream_t stream) {
  const float* x    = (const float*)d_in[0];
  const float* w    = (const float*)d_in[1];
  const float* cent = (const float*)d_in[2];
  float* out = (float*)d_out;

  ushort* a2        = (ushort*)d_ws;
  float*  asum_part = (float*)((char*)d_ws + A2_ELEMS * sizeof(ushort));

  netvlad_assign<<<dim3(PTILES * N_DIM), 256, 0, stream>>>(x, w, a2, asum_part);
  netvlad_agg   <<<dim3(8, N_DIM),       256, 0, stream>>>(x, a2, asum_part, cent, out);
}